// Round 7
// baseline (10320.262 us; speedup 1.0000x reference)
//
#include <hip/hip_runtime.h>
#include <hip/hip_bf16.h>
#include <stdint.h>

#define B_ 128
#define T_ 256
#define S_ 256
#define I_ 512
#define H_ 512
#define RSLOT 32   // ring depth

typedef __attribute__((ext_vector_type(8))) short short8;
typedef __attribute__((ext_vector_type(4))) float f32x4;
typedef unsigned short ushort_t;
typedef unsigned long long u64;

__device__ __forceinline__ float bf2f(ushort_t u){
  union{ unsigned int i; float f;} v; v.i = ((unsigned int)u)<<16; return v.f;
}
__device__ __forceinline__ ushort_t f2bf(float f){
  union{ unsigned int i; float f;} v; v.f=f;
  unsigned int x=v.i; unsigned int r = x + 0x7fffu + ((x>>16)&1u);
  return (ushort_t)(r>>16);
}
__device__ __forceinline__ float sigm(float x){ return 1.f/(1.f + __expf(-x)); }
__device__ __forceinline__ float tanh_s(float x){
  float a = fabsf(x);
  float e = __expf(-2.f*a);
  float t = (1.f - e)/(1.f + e);
  return x < 0.f ? -t : t;
}

__device__ __forceinline__ f32x4 MFMA16(short8 a, short8 b, f32x4 c){
  typedef __attribute__((ext_vector_type(8))) __bf16 bf16x8;
  return __builtin_amdgcn_mfma_f32_16x16x32_bf16(
      __builtin_bit_cast(bf16x8, a), __builtin_bit_cast(bf16x8, b), c, 0, 0, 0);
}

// fabric (agent-scope) 8B store: visible device-wide after vmcnt drain + full gbar
__device__ __forceinline__ void fab_store_u64(void* p, u64 v){
  __hip_atomic_store((u64*)p, v, __ATOMIC_RELAXED, __HIP_MEMORY_SCOPE_AGENT);
}

// ---------------- converts / init ----------------

__global__ void k_cvt_bf16(const float* __restrict__ src, ushort_t* __restrict__ dst, int n){
  int i = (blockIdx.x*blockDim.x + threadIdx.x)*4;
  int stride = gridDim.x*blockDim.x*4;
  for (; i < n; i += stride){
    float4 v = *(const float4*)(src + i);
    ushort4 o; o.x=f2bf(v.x); o.y=f2bf(v.y); o.z=f2bf(v.z); o.w=f2bf(v.w);
    *(ushort4*)(dst + i) = o;
  }
}

__global__ void k_init_state(const float* __restrict__ h0, const float* __restrict__ c0,
                             ushort_t* __restrict__ hring0, float* __restrict__ cyb){
  int i = blockIdx.x*blockDim.x + threadIdx.x; // 65536 total
  hring0[i] = f2bf(h0[i]);
  cyb[i] = c0[i];
}

__global__ void k_zero_bar(int* f){
  f[threadIdx.x] = 0;   // flags[256]
}

// ---------------- precompute GEMM (Xg) ----------------
__global__ __launch_bounds__(256) void k_gemm_bt(
    const float* __restrict__ A, const float* __restrict__ Bm,
    ushort_t* __restrict__ C, int M, int N, int K,
    const float* __restrict__ bias0, const float* __restrict__ bias1){
  __shared__ ushort_t Asm[128][40];
  __shared__ ushort_t Bsm[128][40];
  const int tid = threadIdx.x;
  const int mBase = blockIdx.x*128, nBase = blockIdx.y*128;
  const int l = tid & 63, wv = tid >> 6;
  const int wm = (wv>>1)*64, wn = (wv&1)*64;
  const int lr = l & 15, lq = l >> 4;
  const int srow = tid >> 1, scol = (tid & 1)*16;
  const float* Ap = A + (size_t)(mBase + srow)*K + scol;
  const float* Bp = Bm + (size_t)(nBase + srow)*K + scol;

  f32x4 acc[4][4];
  #pragma unroll
  for (int i=0;i<4;i++)
    #pragma unroll
    for (int j=0;j<4;j++) acc[i][j] = (f32x4)0.f;

  for (int k0 = 0; k0 < K; k0 += 32){
    float4 a0 = *(const float4*)(Ap + k0);
    float4 a1 = *(const float4*)(Ap + k0 + 4);
    float4 a2 = *(const float4*)(Ap + k0 + 8);
    float4 a3 = *(const float4*)(Ap + k0 + 12);
    float4 b0 = *(const float4*)(Bp + k0);
    float4 b1 = *(const float4*)(Bp + k0 + 4);
    float4 b2 = *(const float4*)(Bp + k0 + 8);
    float4 b3 = *(const float4*)(Bp + k0 + 12);
    __syncthreads();
    {
      ushort4 w;
      w.x=f2bf(a0.x); w.y=f2bf(a0.y); w.z=f2bf(a0.z); w.w=f2bf(a0.w);
      *(ushort4*)&Asm[srow][scol+0]  = w;
      w.x=f2bf(a1.x); w.y=f2bf(a1.y); w.z=f2bf(a1.z); w.w=f2bf(a1.w);
      *(ushort4*)&Asm[srow][scol+4]  = w;
      w.x=f2bf(a2.x); w.y=f2bf(a2.y); w.z=f2bf(a2.z); w.w=f2bf(a2.w);
      *(ushort4*)&Asm[srow][scol+8]  = w;
      w.x=f2bf(a3.x); w.y=f2bf(a3.y); w.z=f2bf(a3.z); w.w=f2bf(a3.w);
      *(ushort4*)&Asm[srow][scol+12] = w;
      w.x=f2bf(b0.x); w.y=f2bf(b0.y); w.z=f2bf(b0.z); w.w=f2bf(b0.w);
      *(ushort4*)&Bsm[srow][scol+0]  = w;
      w.x=f2bf(b1.x); w.y=f2bf(b1.y); w.z=f2bf(b1.z); w.w=f2bf(b1.w);
      *(ushort4*)&Bsm[srow][scol+4]  = w;
      w.x=f2bf(b2.x); w.y=f2bf(b2.y); w.z=f2bf(b2.z); w.w=f2bf(b2.w);
      *(ushort4*)&Bsm[srow][scol+8]  = w;
      w.x=f2bf(b3.x); w.y=f2bf(b3.y); w.z=f2bf(b3.z); w.w=f2bf(b3.w);
      *(ushort4*)&Bsm[srow][scol+12] = w;
    }
    __syncthreads();
    short8 aF[4], bF[4];
    #pragma unroll
    for (int i=0;i<4;i++) aF[i] = *(const short8*)&Asm[wm + i*16 + lr][lq*8];
    #pragma unroll
    for (int j=0;j<4;j++) bF[j] = *(const short8*)&Bsm[wn + j*16 + lr][lq*8];
    #pragma unroll
    for (int i=0;i<4;i++)
      #pragma unroll
      for (int j=0;j<4;j++)
        acc[i][j] = MFMA16(aF[i], bF[j], acc[i][j]);
  }

  #pragma unroll
  for (int j=0;j<4;j++){
    int col = nBase + wn + j*16 + lr;
    float bsum = bias0[col] + bias1[col];
    #pragma unroll
    for (int i=0;i<4;i++){
      int row0 = mBase + wm + i*16 + lq*4;
      #pragma unroll
      for (int r=0;r<4;r++)
        C[(size_t)(row0+r)*N + col] = f2bf(acc[i][j][r] + bsum);
    }
  }
}

// ---------------- fence-free grid barrier (proven rounds 3-4) ----------------
__device__ __forceinline__ void gbar(int* flags, int gen){
  __syncthreads();
  const int tid = threadIdx.x;
  if (tid == 0)
    __hip_atomic_store(&flags[blockIdx.x], gen, __ATOMIC_RELAXED, __HIP_MEMORY_SCOPE_AGENT);
  if (tid < 256){
    while (__hip_atomic_load(&flags[tid], __ATOMIC_RELAXED, __HIP_MEMORY_SCOPE_AGENT) < gen)
      __builtin_amdgcn_s_sleep(2);
  }
  __syncthreads();
  asm volatile("" ::: "memory");
}

// ---------------- persistent recurrence kernel ----------------
// 256 blocks x 512 threads, 1 block/CU. ctx in LDS for the whole kernel
// (XOR-swizzled). Weights pinned in registers. ALL cross-block flows use the
// proven discipline: fabric store -> full grid barrier -> plain cached read.

__global__ __launch_bounds__(512) void k_persist(
    const ushort_t* __restrict__ Xg, const float* __restrict__ ctx,
    const ushort_t* __restrict__ Whb, const ushort_t* __restrict__ Woutb,
    const ushort_t* __restrict__ Winb,
    ushort_t* hring, ushort_t* hyring, ushort_t* wcring,
    float* cyb, float* psmail, float* out, float* hf, float* cf,
    int* flags)
{
  extern __shared__ __align__(16) char ctx_s[];   // 131072 B: [256 s][256 h-half] bf16, swizzled

  __shared__ __align__(16) union {
    struct { float red[8][256]; ushort_t pk[256]; } a;
    struct { float hy[512]; float tg[256]; float ps[256]; float sc[256];
             float p[256]; float inv; float pad;
             float pacc[16][256]; ushort_t pk[256]; } b;
  } sh;

  const int pbid = blockIdx.x;
  const int tid = threadIdx.x;
  const int l = tid & 63, wv = tid >> 6;     // 8 waves
  const int lr = l & 15, lq = l >> 4;

  // ---- pin weight fragments in registers ----
  const int bm = pbid >> 5, hc = pbid & 31;       // phase A / C tiles
  const int gate = wv & 3, khalf = wv >> 2;
  short8 whr[8];
  #pragma unroll
  for (int kk=0;kk<8;kk++)
    whr[kk] = *(const short8*)(Whb + (size_t)(gate*512 + hc*16 + lr)*512
                               + khalf*256 + lq*8 + kk*32);
  short8 wor[4];
  #pragma unroll
  for (int kk=0;kk<4;kk++)
    wor[kk] = *(const short8*)(Woutb + (size_t)(hc*16 + lr)*1024
                               + wv*128 + lq*8 + kk*32);

  const int bB = pbid >> 1, half = pbid & 1;      // phase B ids

  // ---- one-time: stage this block's ctx half into LDS (swizzled) ----
  {
    const float* cp = ctx + (size_t)bB*512 + half*256 + (tid & 63)*4;
    #pragma unroll 4
    for (int i = 0; i < 32; ++i){
      int s = i*8 + (tid >> 6);
      float4 v = *(const float4*)(cp + (size_t)s*65536);
      ushort4 o; o.x=f2bf(v.x); o.y=f2bf(v.y); o.z=f2bf(v.z); o.w=f2bf(v.w);
      int boff = ((tid & 63)*8) ^ ((s & 7) << 4);
      *(ushort4*)(ctx_s + s*512 + boff) = o;
    }
  }
  __syncthreads();

  int gen = 0;
  for (int t = 0; t < T_; ++t){
    const size_t slotC = (size_t)(t & (RSLOT-1)) * 65536;
    const int slotI = t & (RSLOT-1);

    // ======== Phase A: gates = Xg[:,t,:] + h @ Wh^T ; LSTM pointwise ========
    {
      ushort_t x0=0,x1=0,x2=0,x3=0; float co = 0.f;
      if (tid < 256){
        const int b = bm*16 + (tid>>4), h = hc*16 + (tid&15);
        const ushort_t* xg = Xg + ((size_t)b*T_ + t)*2048 + h;
        x0 = xg[0]; x1 = xg[512]; x2 = xg[1024]; x3 = xg[1536];
        co = cyb[b*512 + h];
      }
      f32x4 acc = (f32x4)0.f;
      const ushort_t* ap = hring + slotC + (size_t)(bm*16 + lr)*512 + khalf*256 + lq*8;
      short8 hv8[8];
      #pragma unroll
      for (int kk=0;kk<8;kk++) hv8[kk] = *(const short8*)(ap + kk*32);
      #pragma unroll
      for (int kk=0;kk<8;kk++) acc = MFMA16(hv8[kk], whr[kk], acc);
      #pragma unroll
      for (int r=0;r<4;r++) sh.a.red[wv][(lq*4+r)*16+lr] = acc[r];
      __syncthreads();
      if (tid < 256){
        const int b = bm*16 + (tid>>4), h = hc*16 + (tid&15);
        float gi  = sh.a.red[0][tid] + sh.a.red[4][tid] + bf2f(x0);
        float gf  = sh.a.red[1][tid] + sh.a.red[5][tid] + bf2f(x1);
        float gg  = sh.a.red[2][tid] + sh.a.red[6][tid] + bf2f(x2);
        float go_ = sh.a.red[3][tid] + sh.a.red[7][tid] + bf2f(x3);
        float cn = sigm(gf)*co + sigm(gi)*tanh_s(gg);
        float hn = sigm(go_)*tanh_s(cn);
        cyb[b*512 + h] = cn;
        sh.a.pk[tid] = f2bf(hn);
        if (t == T_-1) cf[b*512 + h] = cn;
      }
      __syncthreads();
      if (tid < 64){
        u64 v = *(u64*)&sh.a.pk[tid*4];
        fab_store_u64(hyring + slotC + (size_t)(bm*16 + (tid>>2))*512
                      + hc*16 + (tid&3)*4, v);
      }
    }
    gbar(flags, ++gen);

    // ======== Phase B1: target GEMV + partial scores -> mailbox ========
    {
      // hy[b] -> LDS (f32)
      if (tid < 128){
        ushort4 v = *(const ushort4*)(hyring + slotC + (size_t)bB*512 + tid*4);
        sh.b.hy[tid*4+0]=bf2f(v.x); sh.b.hy[tid*4+1]=bf2f(v.y);
        sh.b.hy[tid*4+2]=bf2f(v.z); sh.b.hy[tid*4+3]=bf2f(v.w);
      }
      __syncthreads();
      // target_half[j] = sum_k hy[k]*Win[half*256+j][k]  (Win L2-resident)
      {
        const int j = tid >> 1, kh = tid & 1;
        const ushort_t* wp = Winb + (size_t)(half*256 + j)*512 + kh*256;
        float d = 0.f;
        #pragma unroll
        for (int c = 0; c < 32; ++c){
          short8 w8 = *(const short8*)(wp + c*8);
          #pragma unroll
          for (int e=0;e<8;e++) d += bf2f((ushort_t)w8[e]) * sh.b.hy[kh*256 + c*8 + e];
        }
        d += __shfl_xor(d, 1);
        if (kh == 0) sh.b.tg[j] = d;
      }
      __syncthreads();
      // partial scores over this h-half: ps[s] = sum_j tg[j]*ctx_s[s][j]
      {
        const int s = tid >> 1, qh = tid & 1;
        const int swz = (s & 7) << 4;
        float d = 0.f;
        #pragma unroll
        for (int c = 0; c < 16; ++c){
          int eb = c*16 + qh*8;                       // element base 0..255
          short8 cv = *(const short8*)(ctx_s + s*512 + ((eb*2) ^ swz));
          #pragma unroll
          for (int e=0;e<8;e++) d += bf2f((ushort_t)cv[e]) * sh.b.tg[eb + e];
        }
        d += __shfl_xor(d, 1);
        if (qh == 0) sh.b.ps[s] = d;
      }
      __syncthreads();
      // mailbox store; visibility via the FULL grid barrier below (proven pattern)
      {
        float* mymail = psmail + ((size_t)(bB*2 + half)*RSLOT + slotI)*256;
        if (tid < 128)
          fab_store_u64(mymail + tid*2, *(u64*)&sh.b.ps[tid*2]);
      }
    }
    gbar(flags, ++gen);

    // ======== Phase B2: combine scores, softmax, wc ========
    {
      {
        const float* budp = psmail + ((size_t)(bB*2 + (half^1))*RSLOT + slotI)*256;
        if (tid < 128){
          float2 f2 = *(const float2*)(budp + tid*2);
          sh.b.sc[tid*2]   = sh.b.ps[tid*2]   + f2.x;
          sh.b.sc[tid*2+1] = sh.b.ps[tid*2+1] + f2.y;
        }
      }
      __syncthreads();
      // softmax (wave 0)
      if (wv == 0){
        float v0=sh.b.sc[l], v1=sh.b.sc[l+64], v2=sh.b.sc[l+128], v3=sh.b.sc[l+192];
        float m = fmaxf(fmaxf(v0,v1), fmaxf(v2,v3));
        #pragma unroll
        for (int off=32; off; off>>=1) m = fmaxf(m, __shfl_xor(m, off));
        float e0=__expf(v0-m), e1=__expf(v1-m), e2=__expf(v2-m), e3=__expf(v3-m);
        float s4 = (e0+e1)+(e2+e3);
        #pragma unroll
        for (int off=32; off; off>>=1) s4 += __shfl_xor(s4, off);
        sh.b.p[l]=e0; sh.b.p[l+64]=e1; sh.b.p[l+128]=e2; sh.b.p[l+192]=e3;
        if (l==0) sh.b.inv = 1.f/s4;
      }
      __syncthreads();
      // wc_half from LDS ctx: thread = (h-group g of 8 elems, s-strip p of 16)
      {
        const int g = tid & 31, p = tid >> 5;
        float a8[8];
        #pragma unroll
        for (int e=0;e<8;e++) a8[e]=0.f;
        #pragma unroll
        for (int j=0;j<16;j++){
          int s = p*16 + j;
          short8 cv = *(const short8*)(ctx_s + s*512 + ((g*16) ^ ((s&7)<<4)));
          float pw = sh.b.p[s];
          #pragma unroll
          for (int e=0;e<8;e++) a8[e] += pw * bf2f((ushort_t)cv[e]);
        }
        #pragma unroll
        for (int e=0;e<8;e++) sh.b.pacc[p][g*8+e] = a8[e];
      }
      __syncthreads();
      if (tid < 256){
        float ssum = 0.f;
        #pragma unroll
        for (int p2=0;p2<16;p2++) ssum += sh.b.pacc[p2][tid];
        sh.b.pk[tid] = f2bf(ssum * sh.b.inv);
      }
      __syncthreads();
      if (tid < 64){
        u64 v = *(u64*)&sh.b.pk[tid*4];
        fab_store_u64(wcring + slotC + (size_t)bB*512 + half*256 + tid*4, v);
      }
    }
    gbar(flags, ++gen);

    // ======== Phase C: h_tilde = tanh([wc|hy] @ W_out^T) ========
    {
      f32x4 acc = (f32x4)0.f;
      const ushort_t* ap = (wv < 4 ? wcring : hyring) + slotC
                           + (size_t)(bm*16 + lr)*512 + (wv&3)*128 + lq*8;
      short8 av[4];
      #pragma unroll
      for (int kk=0;kk<4;kk++) av[kk] = *(const short8*)(ap + kk*32);
      #pragma unroll
      for (int kk=0;kk<4;kk++) acc = MFMA16(av[kk], wor[kk], acc);
      #pragma unroll
      for (int r=0;r<4;r++) sh.a.red[wv][(lq*4+r)*16+lr] = acc[r];
      __syncthreads();
      if (tid < 256){
        float s = 0.f;
        #pragma unroll
        for (int w=0;w<8;w++) s += sh.a.red[w][tid];
        float v = tanh_s(s);
        const int b = bm*16 + (tid>>4), n = hc*16 + (tid&15);
        out[((size_t)b*T_ + t)*512 + n] = v;
        sh.a.pk[tid] = f2bf(v);
        if (t == T_-1) hf[b*512 + n] = v;
      }
      __syncthreads();
      if (tid < 64){
        u64 v = *(u64*)&sh.a.pk[tid*4];
        size_t slotN = (size_t)((t+1) & (RSLOT-1)) * 65536;
        fab_store_u64(hring + slotN + (size_t)(bm*16 + (tid>>2))*512
                      + hc*16 + (tid&3)*4, v);
      }
    }
    gbar(flags, ++gen);
  }
}

// ---------------- host ----------------

extern "C" void kernel_launch(void* const* d_in, const int* in_sizes, int n_in,
                              void* d_out, int out_size, void* d_ws, size_t ws_size,
                              hipStream_t stream){
  const float* x    = (const float*)d_in[0];
  const float* h0   = (const float*)d_in[1];
  const float* c0   = (const float*)d_in[2];
  const float* ctx  = (const float*)d_in[3];
  const float* Wi   = (const float*)d_in[4];
  const float* bi   = (const float*)d_in[5];
  const float* Wh   = (const float*)d_in[6];
  const float* bh   = (const float*)d_in[7];
  const float* Win  = (const float*)d_in[8];
  const float* Wout = (const float*)d_in[9];

  char* ws = (char*)d_ws;
  ushort_t* Xg     = (ushort_t*)(ws);                 // 134217728
  ushort_t* Whb    = (ushort_t*)(ws + 134217728);     //   2097152
  ushort_t* Woutb  = (ushort_t*)(ws + 136314880);     //   1048576
  ushort_t* Winb   = (ushort_t*)(ws + 137363456);     //    524288
  ushort_t* hring  = (ushort_t*)(ws + 137887744);     //   4194304 (32 slots)
  ushort_t* hyring = (ushort_t*)(ws + 142082048);     //   4194304
  ushort_t* wcring = (ushort_t*)(ws + 146276352);     //   4194304
  float*    cyb    = (float*)   (ws + 150470656);     //    262144
  float*    psmail = (float*)   (ws + 150732800);     //   8388608
  int*      flags  = (int*)     (ws + 159121408);     //      1024

  float* out = (float*)d_out;
  float* hf  = out + (size_t)B_*T_*H_;
  float* cf  = hf + (size_t)B_*H_;

  // allow 128 KB dynamic LDS (static ~23 KB + 128 KB < 160 KB/CU)
  hipFuncSetAttribute((const void*)k_persist,
                      hipFuncAttributeMaxDynamicSharedMemorySize, 131072);

  // precompute / converts
  k_cvt_bf16<<<512, 256, 0, stream>>>(Wh, Whb, 4*H_*H_);
  k_cvt_bf16<<<512, 256, 0, stream>>>(Wout, Woutb, H_*2*H_);
  k_cvt_bf16<<<256, 256, 0, stream>>>(Win, Winb, H_*H_);
  k_init_state<<<256, 256, 0, stream>>>(h0, c0, hring, cyb);
  k_zero_bar<<<1, 256, 0, stream>>>(flags);

  // Xg = x @ Wi^T + (bi + bh)   [32768 x 2048], K=512
  k_gemm_bt<<<dim3(256,16), 256, 0, stream>>>(x, Wi, Xg, B_*T_, 4*H_, I_, bi, bh);

  // whole recurrence; ctx resident in LDS; all exchanges via full gbar
  k_persist<<<256, 512, 131072, stream>>>(Xg, ctx, Whb, Woutb, Winb,
                                          hring, hyring, wcring,
                                          cyb, psmail, out, hf, cf,
                                          flags);
}